// Round 13
// baseline (643.454 us; speedup 1.0000x reference)
//
#include <hip/hip_runtime.h>

#define DD 1024
#define FF 4096
#define LL 24
#define VV 50277
#define NB 1024
#define AG __HIP_MEMORY_SCOPE_AGENT

typedef unsigned u32;
typedef float v4f __attribute__((ext_vector_type(4)));

// ---------------- reductions ----------------

__device__ __forceinline__ float wave_sum(float v) {
#pragma unroll
    for (int o = 32; o > 0; o >>= 1) v += __shfl_xor(v, o, 64);
    return v;
}

// single-pass LayerNorm over D=1024, 256-thread block
__device__ __forceinline__ v4f ln_fast(v4f x, const float* __restrict__ w,
                                       const float* __restrict__ b,
                                       float* scr, int t) {
    float s1 = x[0] + x[1] + x[2] + x[3];
    float s2 = x[0]*x[0] + x[1]*x[1] + x[2]*x[2] + x[3]*x[3];
    s1 = wave_sum(s1); s2 = wave_sum(s2);
    int wv = t >> 6;
    __syncthreads();
    if ((t & 63) == 0) { scr[wv] = s1; scr[4 + wv] = s2; }
    __syncthreads();
    float S1 = scr[0] + scr[1] + scr[2] + scr[3];
    float S2 = scr[4] + scr[5] + scr[6] + scr[7];
    float m = S1 * (1.0f / 1024.0f);
    float var = S2 * (1.0f / 1024.0f) - m * m;
    float rs = rsqrtf(var + 1e-5f);
    v4f w4 = ((const v4f*)w)[t], b4 = ((const v4f*)b)[t];
    return (x - m) * rs * w4 + b4;
}

__device__ __forceinline__ v4f mixv(v4f n, v4f s, v4f m) { return n * m + s * (1.0f - m); }

__device__ __forceinline__ float dotv(v4f a, v4f x) {
    return fmaf(a[0], x[0], fmaf(a[1], x[1], fmaf(a[2], x[2], a[3] * x[3])));
}

struct Row { v4f a, b, c, d; };

__device__ __forceinline__ void row_load(Row& r, const float* p, int lane) {
    const v4f* q = (const v4f*)p;
    r.a = q[lane]; r.b = q[lane + 64]; r.c = q[lane + 128]; r.d = q[lane + 192];
}
__device__ __forceinline__ void row_pin(Row& r) {
    asm volatile("" : "+v"(r.a), "+v"(r.b), "+v"(r.c), "+v"(r.d));
}
__device__ __forceinline__ float row_dot(const Row& r, const v4f* v, int lane) {
    return dotv(r.a, v[lane]) + dotv(r.b, v[lane + 64]) +
           dotv(r.c, v[lane + 128]) + dotv(r.d, v[lane + 192]);
}

// ---------------- coherent data ops (LLC, sc0sc1, relaxed agent) -----------

__device__ __forceinline__ void astore_f(float* p, float v) {
    __hip_atomic_store(p, v, __ATOMIC_RELAXED, AG);
}
__device__ __forceinline__ void cload(v4f& d, const float* p) {
    asm volatile("global_load_dwordx4 %0, %1, off sc0 sc1" : "=v"(d) : "v"(p));
}
__device__ __forceinline__ void cwait1(v4f& a) {
    asm volatile("s_waitcnt vmcnt(0)" : "+v"(a));
}
__device__ __forceinline__ void cwait4(v4f& a, v4f& b, v4f& c, v4f& d) {
    asm volatile("s_waitcnt vmcnt(0)" : "+v"(a), "+v"(b), "+v"(c), "+v"(d));
}

// ---------------- split push-release barrier: arrive | prefetch | wait -----
// Wave 0 issues NO VMEM between arrive and wait -> t0's RMW/poll are clean.
// Waves 1-3 stream next-stage weights in the window; their drain happens at
// the exit __syncthreads, overlapped (per block) with release propagation.

__device__ __forceinline__ void bar_arrive(u32* sync, u32 ev, int b, int t) {
    __syncthreads();   // drains all waves: data stores retired to LLC
    if (t == 0) {
        u32* shard = sync + (b & 7) * 32;
        u32* l2c   = sync + 8 * 32;
        u32* rel0  = sync + 9 * 32;
        u32 old = __hip_atomic_fetch_add(shard, 1u, __ATOMIC_RELAXED, AG);
        if (old == 128u * ev - 1u) {                 // shard-last
            u32 o2 = __hip_atomic_fetch_add(l2c, 1u, __ATOMIC_RELAXED, AG);
            if (o2 == 8u * ev - 1u) {                // global-last: push release
#pragma unroll
                for (int i = 0; i < 8; ++i)
                    __hip_atomic_store(rel0 + i * 32, ev, __ATOMIC_RELAXED, AG);
            }
        }
    }
    __builtin_amdgcn_sched_barrier(0);
}

__device__ __forceinline__ void bar_wait(u32* sync, u32 ev, int b, int t) {
    __builtin_amdgcn_sched_barrier(0);
    if (t == 0) {
        u32* myrel = sync + 9 * 32 + (b & 7) * 32;
        while (__hip_atomic_load(myrel, __ATOMIC_RELAXED, AG) < ev)
            __builtin_amdgcn_s_sleep(2);
    }
    __syncthreads();   // waves 1-3 drain their window prefetch here
}

// ---------------- the whole network, one kernel ----------------
// 1024 blocks x 256 threads, 4 blocks/CU. Block b owns channel b of
// kw/vw/rw/ow/fvw/frw outputs and fkw rows 4b..4b+3.
// Wave roles (Rows in registers; <=2 live per wave):
//   stage A dots: w2: kw,vw  w1: rw        (loaded in W4 of prev layer)
//   stage B dot : w3: ow                   (loaded in W4)
//   stage C dots: w1: fkw0,1  w3: fkw2,3  w2: frw   (W1/W2)
//   stage D dots: w1: fvw q0,q1  w3: q2,q3           (W3)

__global__ __launch_bounds__(256, 4) void rwkv_all(
    const float* __restrict__ token_embd, const float* __restrict__ state,
    const float* __restrict__ emb_ln_w, const float* __restrict__ emb_ln_b,
    const float* __restrict__ ln1_w, const float* __restrict__ ln1_b,
    const float* __restrict__ ln2_w, const float* __restrict__ ln2_b,
    const float* __restrict__ att_tmk, const float* __restrict__ att_tmv,
    const float* __restrict__ att_tmr, const float* __restrict__ att_tf,
    const float* __restrict__ att_td,
    const float* __restrict__ att_kw, const float* __restrict__ att_vw,
    const float* __restrict__ att_rw, const float* __restrict__ att_ow,
    const float* __restrict__ ffn_tmk, const float* __restrict__ ffn_tmr,
    const float* __restrict__ ffn_kw, const float* __restrict__ ffn_vw,
    const float* __restrict__ ffn_rw,
    const float* __restrict__ out_ln_w, const float* __restrict__ out_ln_b,
    const float* __restrict__ head_w,
    float* __restrict__ logits, float* __restrict__ st_out_base,
    float* __restrict__ ws, u32* __restrict__ sync) {

    __shared__ __align__(16) v4f s_buf[1024];   // mixes / k2 staging
    __shared__ __align__(16) v4f s_vec[256];    // rab / head vector
    __shared__ float scr[8];
    __shared__ float s_kvr[3];
    __shared__ float s_part[8];
    __shared__ float s_xsave;

    const int t = threadIdx.x, lane = t & 63, w = t >> 6, b = blockIdx.x;

    float* rab = ws;            // 1024
    float* xB  = ws + 1024;     // 1024
    float* k2  = ws + 2048;     // 4096
    float* xD  = ws + 6144;     // 1024

    // ---- prologue: layer-0 stage-A/B rows (matches W4 layout) ----
    Row rA, rB;
    if (w == 2)      { row_load(rA, att_kw + (size_t)b * DD, lane);
                       row_load(rB, att_vw + (size_t)b * DD, lane); }
    else if (w == 1)   row_load(rA, att_rw + (size_t)b * DD, lane);
    else if (w == 3)   row_load(rA, att_ow + (size_t)b * DD, lane);
    if (w) { row_pin(rA); }

    v4f xv = ((const v4f*)token_embd)[t];
    xv = ln_fast(xv, emb_ln_w, emb_ln_b, scr, t);

    u32 ev = 0;
#pragma unroll 1
    for (int i = 0; i < LL; ++i) {
        const size_t oD = (size_t)i * DD;
        const float* st = state + (size_t)i * 5 * DD;
        float* sto = st_out_base + (size_t)i * 5 * DD;
        const float scale = ((i + 1) % 6 == 0) ? 0.5f : 1.0f;

        // ===== stage A: LN1 + mix + {k,v,r} dots + in-block wkv ============
        if (i > 0) { cload(xv, xD + 4 * t); cwait1(xv); }
        if (t == (b >> 2)) s_xsave = xv[b & 3];          // x_in[b]
        v4f n = ln_fast(xv, ln1_w + oD, ln1_b + oD, scr, t);
        if (b == 0) ((v4f*)(sto + DD))[t] = n;           // new_st[1] = xn
        {
            v4f sa = ((const v4f*)(st + DD))[t];
            s_buf[t]       = mixv(n, sa, ((const v4f*)(att_tmk + oD))[t]);
            s_buf[256 + t] = mixv(n, sa, ((const v4f*)(att_tmv + oD))[t]);
            s_buf[512 + t] = mixv(n, sa, ((const v4f*)(att_tmr + oD))[t]);
        }
        __syncthreads();
        if (w == 2) {
            float a0 = wave_sum(row_dot(rA, &s_buf[0], lane));
            float a1 = wave_sum(row_dot(rB, &s_buf[256], lane));
            if (lane == 0) { s_kvr[0] = a0; s_kvr[1] = a1; }
        } else if (w == 1) {
            float a2 = wave_sum(row_dot(rA, &s_buf[512], lane));
            if (lane == 0) s_kvr[2] = a2;
        }
        __syncthreads();
        if (t == 0) {                                    // wkv for channel b
            float kk = s_kvr[0], vv = s_kvr[1];
            float rr = 1.0f / (1.0f + expf(-s_kvr[2]));
            float aa = st[2 * DD + b], bb = st[3 * DD + b], pp = st[4 * DD + b];
            float ww = att_tf[oD + b] + kk;
            float p = fmaxf(pp, ww);
            float e1 = expf(pp - p), e2 = expf(ww - p);
            astore_f(rab + b, rr * ((e1 * aa + e2 * vv) / (e1 * bb + e2)));
            float ww2 = pp + att_td[oD + b];
            float p2 = fmaxf(ww2, kk);
            float f1 = expf(ww2 - p2), f2 = expf(kk - p2);
            sto[2 * DD + b] = f1 * aa + f2 * vv;
            sto[3 * DD + b] = f1 * bb + f2;
            sto[4 * DD + b] = p2;
        }
        // ---- W1: prefetch fkw rows 0,1 (w1) while barrier settles ----
        bar_arrive(sync, ++ev, b, t);
        if (w == 1) {
            const float* fk = ffn_kw + (size_t)i * FF * DD + (size_t)(4 * b) * DD;
            row_load(rA, fk, lane); row_load(rB, fk + DD, lane);
            row_pin(rA); row_pin(rB);
        }
        bar_wait(sync, ev, b, t);

        // ===== stage B: ow dot + residual ===================================
        { v4f rv; cload(rv, rab + 4 * t); cwait1(rv); s_vec[t] = rv; }
        __syncthreads();
        if (w == 3) {
            float acc = wave_sum(row_dot(rA, &s_vec[0], lane));   // ow dies
            if (lane == 0) astore_f(xB + b, s_xsave + acc);
        }
        // ---- W2: prefetch fkw rows 2,3 (w3) + frw (w2) ----
        bar_arrive(sync, ++ev, b, t);
        if (w == 3) {
            const float* fk = ffn_kw + (size_t)i * FF * DD + (size_t)(4 * b + 2) * DD;
            row_load(rA, fk, lane); row_load(rB, fk + DD, lane);
            row_pin(rA); row_pin(rB);
        } else if (w == 2) {
            row_load(rA, ffn_rw + (size_t)i * DD * DD + (size_t)b * DD, lane);
            row_pin(rA);
        }
        bar_wait(sync, ev, b, t);

        // ===== stage C: LN2 + mix + fkw/frw dots (all in regs) =============
        cload(xv, xB + 4 * t); cwait1(xv);
        if (t == (b >> 2)) s_xsave = xv[b & 3];          // x'[b]
        n = ln_fast(xv, ln2_w + oD, ln2_b + oD, scr, t);
        if (b == 0) ((v4f*)sto)[t] = n;                  // new_st[0] = xn2
        {
            v4f sf = ((const v4f*)st)[t];
            s_buf[t]       = mixv(n, sf, ((const v4f*)(ffn_tmk + oD))[t]);
            s_buf[256 + t] = mixv(n, sf, ((const v4f*)(ffn_tmr + oD))[t]);
        }
        __syncthreads();
        if (w == 1) {
            float a0 = wave_sum(row_dot(rA, &s_buf[0], lane));
            float a1 = wave_sum(row_dot(rB, &s_buf[0], lane));
            if (lane == 0) {
                float r0 = fmaxf(a0, 0.f), r1 = fmaxf(a1, 0.f);
                astore_f(k2 + 4 * b + 0, r0 * r0);
                astore_f(k2 + 4 * b + 1, r1 * r1);
            }
        } else if (w == 3) {
            float a2 = wave_sum(row_dot(rA, &s_buf[0], lane));
            float a3 = wave_sum(row_dot(rB, &s_buf[0], lane));
            if (lane == 0) {
                float r2_ = fmaxf(a2, 0.f), r3 = fmaxf(a3, 0.f);
                astore_f(k2 + 4 * b + 2, r2_ * r2_);
                astore_f(k2 + 4 * b + 3, r3 * r3);
            }
        } else if (w == 2) {
            float ar = wave_sum(row_dot(rA, &s_buf[256], lane));
            if (lane == 0) s_part[5] = 1.0f / (1.0f + expf(-ar));  // r2[b]
        }
        // ---- W3: prefetch fvw quarters (w1: q0,q1; w3: q2,q3) ----
        bar_arrive(sync, ++ev, b, t);
        {
            const float* fv = ffn_vw + (size_t)i * DD * FF + (size_t)b * FF;
            if (w == 1) { row_load(rA, fv, lane); row_load(rB, fv + 1024, lane);
                          row_pin(rA); row_pin(rB); }
            else if (w == 3) { row_load(rA, fv + 2048, lane); row_load(rB, fv + 3072, lane);
                               row_pin(rA); row_pin(rB); }
        }
        bar_wait(sync, ev, b, t);

        // ===== stage D: fvw dots + gated residual + rescale ================
        {
            v4f q0, q1, q2, q3;
            cload(q0, k2 + 4 * t);        cload(q1, k2 + 4 * t + 1024);
            cload(q2, k2 + 4 * t + 2048); cload(q3, k2 + 4 * t + 3072);
            cwait4(q0, q1, q2, q3);
            s_buf[t] = q0; s_buf[256 + t] = q1; s_buf[512 + t] = q2; s_buf[768 + t] = q3;
        }
        __syncthreads();
        if (w == 1) {
            float p0 = wave_sum(row_dot(rA, &s_buf[0], lane));
            float p1 = wave_sum(row_dot(rB, &s_buf[256], lane));
            if (lane == 0) { s_part[0] = p0; s_part[1] = p1; }
        } else if (w == 3) {
            float p2 = wave_sum(row_dot(rA, &s_buf[512], lane));
            float p3 = wave_sum(row_dot(rB, &s_buf[768], lane));
            if (lane == 0) { s_part[2] = p2; s_part[3] = p3; }
        }
        __syncthreads();
        if (t == 0) {
            float dsum = s_part[0] + s_part[1] + s_part[2] + s_part[3];
            astore_f(xD + b, (s_xsave + s_part[5] * dsum) * scale);
        }
        // ---- W4: prefetch next layer's kw,vw (w2), rw (w1), ow (w3) ----
        bar_arrive(sync, ++ev, b, t);
        if (i + 1 < LL) {
            const size_t nxt = (size_t)(i + 1) * DD * DD + (size_t)b * DD;
            if (w == 2)      { row_load(rA, att_kw + nxt, lane);
                               row_load(rB, att_vw + nxt, lane);
                               row_pin(rA); row_pin(rB); }
            else if (w == 1) { row_load(rA, att_rw + nxt, lane); row_pin(rA); }
            else if (w == 3) { row_load(rA, att_ow + nxt, lane); row_pin(rA); }
        }
        bar_wait(sync, ev, b, t);
    }

    // ===== head: LN_out + 50277x1024 GEMV (2-deep row pipeline) ============
    cload(xv, xD + 4 * t); cwait1(xv);
    v4f nh = ln_fast(xv, out_ln_w, out_ln_b, scr, t);
    s_vec[t] = nh;
    __syncthreads();
    {
        Row rh;
        int row = 4 * b + w;
        row_load(rh, head_w + (size_t)row * DD, lane);
#pragma unroll 1
        for (int j = 0; j < 13; ++j) {
            Row rn;
            int nrow = row + 4096;
            if (j + 1 < 13 && nrow < VV)
                row_load(rn, head_w + (size_t)nrow * DD, lane);
            if (row < VV) {
                float acc = wave_sum(row_dot(rh, &s_vec[0], lane));
                if (lane == 0) logits[row] = acc;
            }
            rh = rn; row = nrow;
        }
    }
}

// ---------------- launch ----------------

extern "C" void kernel_launch(void* const* d_in, const int* in_sizes, int n_in,
                              void* d_out, int out_size, void* d_ws, size_t ws_size,
                              hipStream_t stream) {
    const float* token_embd = (const float*)d_in[0];
    const float* state      = (const float*)d_in[1];
    const float* emb_ln_w   = (const float*)d_in[2];
    const float* emb_ln_b   = (const float*)d_in[3];
    const float* ln1_w      = (const float*)d_in[4];
    const float* ln1_b      = (const float*)d_in[5];
    const float* ln2_w      = (const float*)d_in[6];
    const float* ln2_b      = (const float*)d_in[7];
    const float* att_tmk    = (const float*)d_in[8];
    const float* att_tmv    = (const float*)d_in[9];
    const float* att_tmr    = (const float*)d_in[10];
    const float* att_tf     = (const float*)d_in[11];
    const float* att_td     = (const float*)d_in[12];
    const float* att_kw     = (const float*)d_in[13];
    const float* att_vw     = (const float*)d_in[14];
    const float* att_rw     = (const float*)d_in[15];
    const float* att_ow     = (const float*)d_in[16];
    const float* ffn_tmk    = (const float*)d_in[17];
    const float* ffn_tmr    = (const float*)d_in[18];
    const float* ffn_kw     = (const float*)d_in[19];
    const float* ffn_vw     = (const float*)d_in[20];
    const float* ffn_rw     = (const float*)d_in[21];
    const float* out_ln_w   = (const float*)d_in[22];
    const float* out_ln_b   = (const float*)d_in[23];
    const float* head_w     = (const float*)d_in[24];

    float* logits = (float*)d_out;
    float* st_out_base = (float*)d_out + VV;

    float* ws = (float*)d_ws;
    u32* sync = (u32*)(ws + 8192);      // 17 lines * 128 B

    hipMemsetAsync(sync, 0, 4096, stream);

    rwkv_all<<<NB, 256, 0, stream>>>(
        token_embd, state, emb_ln_w, emb_ln_b, ln1_w, ln1_b, ln2_w, ln2_b,
        att_tmk, att_tmv, att_tmr, att_tf, att_td,
        att_kw, att_vw, att_rw, att_ow,
        ffn_tmk, ffn_tmr, ffn_kw, ffn_vw, ffn_rw,
        out_ln_w, out_ln_b, head_w,
        logits, st_out_base, ws, sync);
}